// Round 1
// baseline (196.227 us; speedup 1.0000x reference)
//
#include <hip/hip_runtime.h>
#include <hip/hip_bf16.h>
#include <cstdint>

using u16 = unsigned short;
typedef short bf16x8 __attribute__((ext_vector_type(8)));
typedef float f32x4 __attribute__((ext_vector_type(4)));
typedef u16 u16x4 __attribute__((ext_vector_type(4)));
typedef u16 u16x8 __attribute__((ext_vector_type(8)));

// ---------- helpers ----------
__device__ __forceinline__ u16 f2bf(float f) {
  union { float f; uint32_t u; } v; v.f = f;
  uint32_t r = (v.u + 0x7fffu + ((v.u >> 16) & 1u)) >> 16;  // RNE
  return (u16)r;
}

__device__ __forceinline__ void async16(const void* g, void* l) {
  __builtin_amdgcn_global_load_lds(
      (const __attribute__((address_space(1))) uint32_t*)g,
      (__attribute__((address_space(3))) uint32_t*)l, 16, 0, 0);
}

// ---------- convert x: f32 -> bf16 (row-major) ----------
__global__ __launch_bounds__(256) void cvt_kernel(const float* __restrict__ in, u16* __restrict__ out) {
  int i = (blockIdx.x * 256 + threadIdx.x) * 4;
  float4 v = *(const float4*)(in + i);
  u16x4 o;
  o[0] = f2bf(v.x); o[1] = f2bf(v.y); o[2] = f2bf(v.z); o[3] = f2bf(v.w);
  *(u16x4*)(out + i) = o;
}

// ---------- transpose+convert W[k][n] f32 -> Wt[n][k] bf16 ----------
__global__ __launch_bounds__(256) void tconv_kernel(const float* __restrict__ W, u16* __restrict__ Wt) {
  __shared__ float tile[64][65];
  const int tid = threadIdx.x;
  const int k0 = blockIdx.x * 64, n0 = blockIdx.y * 64;
#pragma unroll
  for (int i = 0; i < 4; ++i) {
    int c = i * 256 + tid;          // 0..1023
    int r = c >> 4, c4 = c & 15;
    float4 v = *(const float4*)(W + (size_t)(k0 + r) * 1024 + n0 + c4 * 4);
    tile[r][c4 * 4 + 0] = v.x; tile[r][c4 * 4 + 1] = v.y;
    tile[r][c4 * 4 + 2] = v.z; tile[r][c4 * 4 + 3] = v.w;
  }
  __syncthreads();
#pragma unroll
  for (int i = 0; i < 2; ++i) {
    int c = i * 256 + tid;          // 0..511
    int n = c >> 3, kc = c & 7;
    u16x8 o;
#pragma unroll
    for (int j = 0; j < 8; ++j) o[j] = f2bf(tile[kc * 8 + j][n]);
    *(u16x8*)(Wt + (size_t)(n0 + n) * 1024 + k0 + kc * 8) = o;
  }
}

// ---------- shared GEMM mainloop: C(128x128) = A(128xK) * Bt(128xK)^T, K=1024 ----------
// A, Bt: bf16 row-major with row stride 1024. LDS tiles [128 rows][32 k] with
// 16B-chunk XOR swizzle (chunk ^= row&3), staged via global_load_lds (linear LDS,
// pre-swizzled global source).
__device__ __forceinline__ void stage_ab(const u16* A, const u16* Bt, int m0, int n0, int kt,
                                         u16* As, u16* Bs, int w, int lane) {
#pragma unroll
  for (int c = 0; c < 2; ++c) {
    int chunk = w * 128 + c * 64 + lane;
    int row = chunk >> 2, cc = chunk & 3;
    int koff = kt * 32 + ((cc ^ (row & 3)) << 3);
    const u16* ga = A + (size_t)(m0 + row) * 1024 + koff;
    async16(ga, As + (size_t)(w * 128 + c * 64) * 8);
    const u16* gb = Bt + (size_t)(n0 + row) * 1024 + koff;
    async16(gb, Bs + (size_t)(w * 128 + c * 64) * 8);
  }
}

__device__ __forceinline__ void gemm_mainloop(const u16* A, const u16* Bt, int m0, int n0,
                                              u16 (*As)[4096], u16 (*Bs)[4096], f32x4 acc[4][4]) {
  const int tid = threadIdx.x, w = tid >> 6, lane = tid & 63, lo = lane & 15, hi = lane >> 4;
  const int mb = (w >> 1) * 64, nb = (w & 1) * 64;
  stage_ab(A, Bt, m0, n0, 0, As[0], Bs[0], w, lane);
  __syncthreads();
  for (int kt = 0; kt < 32; ++kt) {
    int cur = kt & 1;
    if (kt + 1 < 32) stage_ab(A, Bt, m0, n0, kt + 1, As[cur ^ 1], Bs[cur ^ 1], w, lane);
    bf16x8 af[4], bfr[4];
#pragma unroll
    for (int i = 0; i < 4; ++i) {
      int ra = mb + i * 16 + lo;
      af[i] = *(const bf16x8*)(As[cur] + ra * 32 + ((hi ^ (ra & 3)) << 3));
      int rb = nb + i * 16 + lo;
      bfr[i] = *(const bf16x8*)(Bs[cur] + rb * 32 + ((hi ^ (rb & 3)) << 3));
    }
#pragma unroll
    for (int i = 0; i < 4; ++i)
#pragma unroll
      for (int j = 0; j < 4; ++j)
        acc[i][j] = __builtin_amdgcn_mfma_f32_16x16x32_bf16(af[i], bfr[j], acc[i][j], 0, 0, 0);
    __syncthreads();
  }
}

// ---------- QKV projection + RoPE + scatter ----------
// mode(blockIdx.z): 0 -> Q (rope), 1 -> K (rope), 2 -> V (write transposed Vt)
__global__ __launch_bounds__(256) void qkv_gemm_kernel(
    const u16* __restrict__ xb, const u16* __restrict__ Wqt, const u16* __restrict__ Wkt,
    const u16* __restrict__ Wvt, u16* __restrict__ Qh, u16* __restrict__ Kh, u16* __restrict__ Vt) {
  __shared__ u16 As[2][4096];
  __shared__ u16 Bs[2][4096];
  const int mode = blockIdx.z;
  const u16* Bt = (mode == 0) ? Wqt : (mode == 1) ? Wkt : Wvt;
  const int m0 = blockIdx.x * 128, n0 = blockIdx.y * 128;
  f32x4 acc[4][4];
  const f32x4 z4 = {0.f, 0.f, 0.f, 0.f};
#pragma unroll
  for (int i = 0; i < 4; ++i)
#pragma unroll
    for (int j = 0; j < 4; ++j) acc[i][j] = z4;
  gemm_mainloop(xb, Bt, m0, n0, As, Bs, acc);

  const int tid = threadIdx.x, w = tid >> 6, lane = tid & 63, lo = lane & 15, hi = lane >> 4;
  const int h = blockIdx.y * 2 + (w & 1);       // head = global col / 64
  const int mrow0 = m0 + (w >> 1) * 64;
  if (mode < 2) {
    u16* Out = (mode == 0) ? Qh : Kh;
    const float invf0 = exp2f(-(float)lo * 0.41524101186092034f);  // 10000^(-lo/32)
    const float invf1 = invf0 * 0.01f;                             // 10000^(-(lo+16)/32)
#pragma unroll
    for (int mi = 0; mi < 4; ++mi) {
#pragma unroll
      for (int r = 0; r < 4; ++r) {
        int tg = mrow0 + mi * 16 + hi * 4 + r;
        int b = tg >> 11, tp = tg & 2047;
        float c0, s0, c1, s1;
        __sincosf((float)tp * invf0, &s0, &c0);
        __sincosf((float)tp * invf1, &s1, &c1);
        size_t obase = ((size_t)(b * 16 + h) * 2048 + tp) * 64 + lo;
#pragma unroll
        for (int nf = 0; nf < 4; ++nf) {
          float v = acc[mi][nf][r];
          float rot = (nf < 2) ? -acc[mi][nf + 2][r] : acc[mi][nf - 2][r];
          float cs = (nf & 1) ? c1 : c0;
          float sn = (nf & 1) ? s1 : s0;
          Out[obase + nf * 16] = f2bf(v * cs + rot * sn);
        }
      }
    }
  } else {
    // V: write Vt[bh][d][t] (transposed for attention PV B-operand)
#pragma unroll
    for (int mi = 0; mi < 4; ++mi) {
      int tg0 = mrow0 + mi * 16 + hi * 4;
      int b = tg0 >> 11, tp0 = tg0 & 2047;
#pragma unroll
      for (int nf = 0; nf < 4; ++nf) {
        int d = nf * 16 + lo;
        u16x4 pk;
#pragma unroll
        for (int r = 0; r < 4; ++r) pk[r] = f2bf(acc[mi][nf][r]);
        *(u16x4*)(Vt + ((size_t)(b * 16 + h) * 64 + d) * 2048 + tp0) = pk;
      }
    }
  }
}

// ---------- flash attention (causal), 64 q-rows per block, 4 waves x 16 rows ----------
__global__ __launch_bounds__(256) void attn_kernel(const u16* __restrict__ Qh, const u16* __restrict__ Kh,
                                                   const u16* __restrict__ Vt, u16* __restrict__ ctx) {
  __shared__ u16 Ks[64 * 64];   // [key][8 chunks of 16B], chunk ^= key&7
  __shared__ u16 Vs[64 * 64];   // [d][8 chunks of 16B] (keys along row), chunk ^= d&7
  __shared__ u16 Ps[4][16 * 72];  // per-wave P transpose buffer, padded stride 72
  const int qt = blockIdx.x, bh = blockIdx.y;
  const int tid = threadIdx.x, w = tid >> 6, lane = tid & 63, lo = lane & 15, hi = lane >> 4;
  const int q0 = qt * 64;
  const u16* Qbase = Qh + ((size_t)bh * 2048 + q0 + w * 16 + lo) * 64 + hi * 8;
  bf16x8 qf0 = *(const bf16x8*)(Qbase);
  bf16x8 qf1 = *(const bf16x8*)(Qbase + 32);
  const f32x4 z4 = {0.f, 0.f, 0.f, 0.f};
  f32x4 O[4];
#pragma unroll
  for (int i = 0; i < 4; ++i) O[i] = z4;
  float m_r[4], l_r[4];
#pragma unroll
  for (int r = 0; r < 4; ++r) { m_r[r] = -1e30f; l_r[r] = 0.f; }
  const size_t kbh = (size_t)bh * 2048 * 64;
  const size_t vbh = (size_t)bh * 64 * 2048;
  const int nkv = qt + 1;

  for (int t = 0; t < nkv; ++t) {
    int kv0 = t * 64;
    // stage K tile and V^T tile (swizzled source, linear LDS dest)
#pragma unroll
    for (int c = 0; c < 2; ++c) {
      int chunk = w * 128 + c * 64 + lane;
      int row = chunk >> 3, cc = chunk & 7;
      int sw = (cc ^ (row & 7)) << 3;
      async16(Kh + kbh + (size_t)(kv0 + row) * 64 + sw, Ks + (size_t)(w * 128 + c * 64) * 8);
      async16(Vt + vbh + (size_t)row * 2048 + kv0 + sw, Vs + (size_t)(w * 128 + c * 64) * 8);
    }
    __syncthreads();

    // S = Q K^T (per wave: 16 q-rows x 64 keys)
    f32x4 s[4];
#pragma unroll
    for (int k2 = 0; k2 < 4; ++k2) {
      int key = k2 * 16 + lo;
      bf16x8 kf0 = *(const bf16x8*)(Ks + key * 64 + ((hi ^ (key & 7)) << 3));
      bf16x8 kf1 = *(const bf16x8*)(Ks + key * 64 + (((4 + hi) ^ (key & 7)) << 3));
      s[k2] = z4;
      s[k2] = __builtin_amdgcn_mfma_f32_16x16x32_bf16(qf0, kf0, s[k2], 0, 0, 0);
      s[k2] = __builtin_amdgcn_mfma_f32_16x16x32_bf16(qf1, kf1, s[k2], 0, 0, 0);
    }

    // scale + causal mask + online softmax (row r lives in lanes with this hi, reg r)
    float alpha[4];
#pragma unroll
    for (int r = 0; r < 4; ++r) {
      int qg = q0 + w * 16 + hi * 4 + r;
      float rmax = -1e30f;
#pragma unroll
      for (int k2 = 0; k2 < 4; ++k2) {
        float sv = s[k2][r] * 0.125f;
        if (kv0 + k2 * 16 + lo > qg) sv = -1e30f;
        s[k2][r] = sv;
        rmax = fmaxf(rmax, sv);
      }
#pragma unroll
      for (int msk = 8; msk; msk >>= 1) rmax = fmaxf(rmax, __shfl_xor(rmax, msk));
      float mnew = fmaxf(m_r[r], rmax);
      alpha[r] = __expf(m_r[r] - mnew);
      m_r[r] = mnew;
      float ps = 0.f;
#pragma unroll
      for (int k2 = 0; k2 < 4; ++k2) {
        float p = __expf(s[k2][r] - mnew);
        ps += p;
        Ps[w][(hi * 4 + r) * 72 + k2 * 16 + lo] = f2bf(p);
      }
#pragma unroll
      for (int msk = 8; msk; msk >>= 1) ps += __shfl_xor(ps, msk);
      l_r[r] = l_r[r] * alpha[r] + ps;
    }

    // PV: O += P @ V   (P via per-wave LDS transpose; DS ops in-order within wave)
    bf16x8 pf0 = *(const bf16x8*)(Ps[w] + lo * 72 + hi * 8);
    bf16x8 pf1 = *(const bf16x8*)(Ps[w] + lo * 72 + 32 + hi * 8);
#pragma unroll
    for (int dt = 0; dt < 4; ++dt) {
      int d = dt * 16 + lo;
#pragma unroll
      for (int r = 0; r < 4; ++r) O[dt][r] *= alpha[r];
      bf16x8 vf0 = *(const bf16x8*)(Vs + d * 64 + ((hi ^ (d & 7)) << 3));
      bf16x8 vf1 = *(const bf16x8*)(Vs + d * 64 + (((4 + hi) ^ (d & 7)) << 3));
      O[dt] = __builtin_amdgcn_mfma_f32_16x16x32_bf16(pf0, vf0, O[dt], 0, 0, 0);
      O[dt] = __builtin_amdgcn_mfma_f32_16x16x32_bf16(pf1, vf1, O[dt], 0, 0, 0);
    }
    __syncthreads();
  }

  // epilogue: ctx[token][h*64+d] bf16
  const int b = bh >> 4, h = bh & 15;
#pragma unroll
  for (int dt = 0; dt < 4; ++dt)
#pragma unroll
    for (int r = 0; r < 4; ++r) {
      int tq = q0 + w * 16 + hi * 4 + r;
      float val = O[dt][r] / l_r[r];
      ctx[((size_t)(b * 2048 + tq)) * 1024 + h * 64 + dt * 16 + lo] = f2bf(val);
    }
}

// ---------- output projection: out = ctx @ w_o (f32 out) ----------
__global__ __launch_bounds__(256) void out_gemm_kernel(const u16* __restrict__ ctxb,
                                                       const u16* __restrict__ Wot,
                                                       float* __restrict__ out) {
  __shared__ u16 As[2][4096];
  __shared__ u16 Bs[2][4096];
  const int m0 = blockIdx.x * 128, n0 = blockIdx.y * 128;
  f32x4 acc[4][4];
  const f32x4 z4 = {0.f, 0.f, 0.f, 0.f};
#pragma unroll
  for (int i = 0; i < 4; ++i)
#pragma unroll
    for (int j = 0; j < 4; ++j) acc[i][j] = z4;
  gemm_mainloop(ctxb, Wot, m0, n0, As, Bs, acc);
  const int tid = threadIdx.x, w = tid >> 6, lane = tid & 63, lo = lane & 15, hi = lane >> 4;
  const int col0 = n0 + (w & 1) * 64 + lo;
#pragma unroll
  for (int mi = 0; mi < 4; ++mi)
#pragma unroll
    for (int r = 0; r < 4; ++r) {
      int tg = m0 + (w >> 1) * 64 + mi * 16 + hi * 4 + r;
#pragma unroll
      for (int nf = 0; nf < 4; ++nf)
        out[(size_t)tg * 1024 + col0 + nf * 16] = acc[mi][nf][r];
    }
}

// ---------- launch ----------
extern "C" void kernel_launch(void* const* d_in, const int* in_sizes, int n_in,
                              void* d_out, int out_size, void* d_ws, size_t ws_size,
                              hipStream_t stream) {
  (void)in_sizes; (void)n_in; (void)out_size; (void)ws_size;
  const float* x  = (const float*)d_in[0];
  const float* wq = (const float*)d_in[1];
  const float* wk = (const float*)d_in[2];
  const float* wv = (const float*)d_in[3];
  const float* wo = (const float*)d_in[4];
  char* ws = (char*)d_ws;
  u16* xb   = (u16*)(ws + (size_t)0);
  u16* Wqt  = (u16*)(ws + ((size_t)8  << 20));
  u16* Wkt  = (u16*)(ws + ((size_t)10 << 20));
  u16* Wvt  = (u16*)(ws + ((size_t)12 << 20));
  u16* Wot  = (u16*)(ws + ((size_t)14 << 20));
  u16* Qh   = (u16*)(ws + ((size_t)16 << 20));
  u16* Kh   = (u16*)(ws + ((size_t)24 << 20));
  u16* Vt   = (u16*)(ws + ((size_t)32 << 20));
  u16* ctxb = (u16*)(ws + ((size_t)40 << 20));

  cvt_kernel<<<4096, 256, 0, stream>>>(x, xb);
  tconv_kernel<<<dim3(16, 16), 256, 0, stream>>>(wq, Wqt);
  tconv_kernel<<<dim3(16, 16), 256, 0, stream>>>(wk, Wkt);
  tconv_kernel<<<dim3(16, 16), 256, 0, stream>>>(wv, Wvt);
  tconv_kernel<<<dim3(16, 16), 256, 0, stream>>>(wo, Wot);
  qkv_gemm_kernel<<<dim3(32, 8, 3), 256, 0, stream>>>(xb, Wqt, Wkt, Wvt, Qh, Kh, Vt);
  attn_kernel<<<dim3(32, 32), 256, 0, stream>>>(Qh, Kh, Vt, ctxb);
  out_gemm_kernel<<<dim3(32, 8), 256, 0, stream>>>(ctxb, Wot, (float*)d_out);
}

// Round 2
// 162.380 us; speedup vs baseline: 1.2084x; 1.2084x over previous
//
#include <hip/hip_runtime.h>
#include <hip/hip_bf16.h>
#include <cstdint>

using u16 = unsigned short;
typedef short bf16x8 __attribute__((ext_vector_type(8)));
typedef float f32x4 __attribute__((ext_vector_type(4)));
typedef u16 u16x4 __attribute__((ext_vector_type(4)));
typedef u16 u16x8 __attribute__((ext_vector_type(8)));

// ---------- helpers ----------
__device__ __forceinline__ u16 f2bf(float f) {
  union { float f; uint32_t u; } v; v.f = f;
  uint32_t r = (v.u + 0x7fffu + ((v.u >> 16) & 1u)) >> 16;  // RNE
  return (u16)r;
}

__device__ __forceinline__ void async16(const void* g, void* l) {
  __builtin_amdgcn_global_load_lds(
      (const __attribute__((address_space(1))) uint32_t*)g,
      (__attribute__((address_space(3))) uint32_t*)l, 16, 0, 0);
}

// ---------- convert x: f32 -> bf16 (row-major) ----------
__global__ __launch_bounds__(256) void cvt_kernel(const float* __restrict__ in, u16* __restrict__ out) {
  int i = (blockIdx.x * 256 + threadIdx.x) * 4;
  float4 v = *(const float4*)(in + i);
  u16x4 o;
  o[0] = f2bf(v.x); o[1] = f2bf(v.y); o[2] = f2bf(v.z); o[3] = f2bf(v.w);
  *(u16x4*)(out + i) = o;
}

// ---------- transpose+convert W[k][n] f32 -> Wt[n][k] bf16 ----------
__global__ __launch_bounds__(256) void tconv_kernel(const float* __restrict__ W, u16* __restrict__ Wt) {
  __shared__ float tile[64][65];
  const int tid = threadIdx.x;
  const int k0 = blockIdx.x * 64, n0 = blockIdx.y * 64;
#pragma unroll
  for (int i = 0; i < 4; ++i) {
    int c = i * 256 + tid;          // 0..1023
    int r = c >> 4, c4 = c & 15;
    float4 v = *(const float4*)(W + (size_t)(k0 + r) * 1024 + n0 + c4 * 4);
    tile[r][c4 * 4 + 0] = v.x; tile[r][c4 * 4 + 1] = v.y;
    tile[r][c4 * 4 + 2] = v.z; tile[r][c4 * 4 + 3] = v.w;
  }
  __syncthreads();
#pragma unroll
  for (int i = 0; i < 2; ++i) {
    int c = i * 256 + tid;          // 0..511
    int n = c >> 3, kc = c & 7;
    u16x8 o;
#pragma unroll
    for (int j = 0; j < 8; ++j) o[j] = f2bf(tile[kc * 8 + j][n]);
    *(u16x8*)(Wt + (size_t)(n0 + n) * 1024 + k0 + kc * 8) = o;
  }
}

// ---------- shared GEMM mainloop: C(128x128) = A(128xK) * Bt(128xK)^T, K=1024 ----------
__device__ __forceinline__ void stage_ab(const u16* A, const u16* Bt, int m0, int n0, int kt,
                                         u16* As, u16* Bs, int w, int lane) {
#pragma unroll
  for (int c = 0; c < 2; ++c) {
    int chunk = w * 128 + c * 64 + lane;
    int row = chunk >> 2, cc = chunk & 3;
    int koff = kt * 32 + ((cc ^ (row & 3)) << 3);
    const u16* ga = A + (size_t)(m0 + row) * 1024 + koff;
    async16(ga, As + (size_t)(w * 128 + c * 64) * 8);
    const u16* gb = Bt + (size_t)(n0 + row) * 1024 + koff;
    async16(gb, Bs + (size_t)(w * 128 + c * 64) * 8);
  }
}

__device__ __forceinline__ void gemm_mainloop(const u16* A, const u16* Bt, int m0, int n0,
                                              u16 (*As)[4096], u16 (*Bs)[4096], f32x4 acc[4][4]) {
  const int tid = threadIdx.x, w = tid >> 6, lane = tid & 63, lo = lane & 15, hi = lane >> 4;
  const int mb = (w >> 1) * 64, nb = (w & 1) * 64;
  stage_ab(A, Bt, m0, n0, 0, As[0], Bs[0], w, lane);
  __syncthreads();
  for (int kt = 0; kt < 32; ++kt) {
    int cur = kt & 1;
    if (kt + 1 < 32) stage_ab(A, Bt, m0, n0, kt + 1, As[cur ^ 1], Bs[cur ^ 1], w, lane);
    bf16x8 af[4], bfr[4];
#pragma unroll
    for (int i = 0; i < 4; ++i) {
      int ra = mb + i * 16 + lo;
      af[i] = *(const bf16x8*)(As[cur] + ra * 32 + ((hi ^ (ra & 3)) << 3));
      int rb = nb + i * 16 + lo;
      bfr[i] = *(const bf16x8*)(Bs[cur] + rb * 32 + ((hi ^ (rb & 3)) << 3));
    }
#pragma unroll
    for (int i = 0; i < 4; ++i)
#pragma unroll
      for (int j = 0; j < 4; ++j)
        acc[i][j] = __builtin_amdgcn_mfma_f32_16x16x32_bf16(af[i], bfr[j], acc[i][j], 0, 0, 0);
    __syncthreads();
  }
}

// ---------- QKV projection + RoPE + scatter ----------
// mode(blockIdx.z): 0 -> Q (rope, pre-scaled by 0.125*log2e), 1 -> K (rope), 2 -> V (transposed Vt)
__global__ __launch_bounds__(256) void qkv_gemm_kernel(
    const u16* __restrict__ xb, const u16* __restrict__ Wqt, const u16* __restrict__ Wkt,
    const u16* __restrict__ Wvt, u16* __restrict__ Qh, u16* __restrict__ Kh, u16* __restrict__ Vt) {
  __shared__ u16 As[2][4096];
  __shared__ u16 Bs[2][4096];
  const int mode = blockIdx.z;
  const u16* Bt = (mode == 0) ? Wqt : (mode == 1) ? Wkt : Wvt;
  const int m0 = blockIdx.x * 128, n0 = blockIdx.y * 128;
  f32x4 acc[4][4];
  const f32x4 z4 = {0.f, 0.f, 0.f, 0.f};
#pragma unroll
  for (int i = 0; i < 4; ++i)
#pragma unroll
    for (int j = 0; j < 4; ++j) acc[i][j] = z4;
  gemm_mainloop(xb, Bt, m0, n0, As, Bs, acc);

  const int tid = threadIdx.x, w = tid >> 6, lane = tid & 63, lo = lane & 15, hi = lane >> 4;
  const int h = blockIdx.y * 2 + (w & 1);       // head = global col / 64
  const int mrow0 = m0 + (w >> 1) * 64;
  if (mode < 2) {
    u16* Out = (mode == 0) ? Qh : Kh;
    // Q gets pre-scaled by 1/sqrt(64) * log2(e) so attention scores are exp2-domain
    const float qscale = (mode == 0) ? 0.18033688011112042f : 1.0f;
    const float invf0 = exp2f(-(float)lo * 0.41524101186092034f);  // 10000^(-lo/32)
    const float invf1 = invf0 * 0.01f;                             // 10000^(-(lo+16)/32)
#pragma unroll
    for (int mi = 0; mi < 4; ++mi) {
#pragma unroll
      for (int r = 0; r < 4; ++r) {
        int tg = mrow0 + mi * 16 + hi * 4 + r;
        int b = tg >> 11, tp = tg & 2047;
        float c0, s0, c1, s1;
        __sincosf((float)tp * invf0, &s0, &c0);
        __sincosf((float)tp * invf1, &s1, &c1);
        size_t obase = ((size_t)(b * 16 + h) * 2048 + tp) * 64 + lo;
#pragma unroll
        for (int nf = 0; nf < 4; ++nf) {
          float v = acc[mi][nf][r];
          float rot = (nf < 2) ? -acc[mi][nf + 2][r] : acc[mi][nf - 2][r];
          float cs = (nf & 1) ? c1 : c0;
          float sn = (nf & 1) ? s1 : s0;
          Out[obase + nf * 16] = f2bf((v * cs + rot * sn) * qscale);
        }
      }
    }
  } else {
    // V: write Vt[bh][d][t] (transposed for attention PV B-operand)
#pragma unroll
    for (int mi = 0; mi < 4; ++mi) {
      int tg0 = mrow0 + mi * 16 + hi * 4;
      int b = tg0 >> 11, tp0 = tg0 & 2047;
#pragma unroll
      for (int nf = 0; nf < 4; ++nf) {
        int d = nf * 16 + lo;
        u16x4 pk;
#pragma unroll
        for (int r = 0; r < 4; ++r) pk[r] = f2bf(acc[mi][nf][r]);
        *(u16x4*)(Vt + ((size_t)(b * 16 + h) * 64 + d) * 2048 + tp0) = pk;
      }
    }
  }
}

// ---------- flash attention (causal), paired q-tiles for balance, dbuf K/V ----------
// block = (qtp, bh): processes q-tiles qtp and 31-qtp => exactly 33 KV-tile iterations/block.
__global__ __launch_bounds__(256) void attn_kernel(const u16* __restrict__ Qh, const u16* __restrict__ Kh,
                                                   const u16* __restrict__ Vt, u16* __restrict__ ctx) {
  __shared__ u16 Ks[2][64 * 64];   // [buf][key][8 chunks of 16B], chunk ^= key&7
  __shared__ u16 Vs[2][64 * 64];   // [buf][d][8 chunks of 16B] (keys along row), chunk ^= d&7
  __shared__ u16 Ps[4][16 * 72];   // per-wave P transpose buffer, padded stride 72
  const int qtp = blockIdx.x, bh = blockIdx.y;
  const int tid = threadIdx.x, w = tid >> 6, lane = tid & 63, lo = lane & 15, hi = lane >> 4;
  const size_t kbh = (size_t)bh * 2048 * 64;
  const size_t vbh = (size_t)bh * 64 * 2048;
  const int b = bh >> 4, h = bh & 15;
  const f32x4 z4 = {0.f, 0.f, 0.f, 0.f};

  for (int half = 0; half < 2; ++half) {
    const int qt = half ? (31 - qtp) : qtp;
    const int q0 = qt * 64;
    const int nkv = qt + 1;

    const u16* Qbase = Qh + ((size_t)bh * 2048 + q0 + w * 16 + lo) * 64 + hi * 8;
    bf16x8 qf0 = *(const bf16x8*)(Qbase);
    bf16x8 qf1 = *(const bf16x8*)(Qbase + 32);

    f32x4 O[4];
#pragma unroll
    for (int i = 0; i < 4; ++i) O[i] = z4;
    float m_r[4], l_r[4];
#pragma unroll
    for (int r = 0; r < 4; ++r) { m_r[r] = -1e30f; l_r[r] = 0.f; }

    // prologue: stage tile 0 (protect buffers from previous half's readers)
    __syncthreads();
    {
      int kv0 = 0;
#pragma unroll
      for (int c = 0; c < 2; ++c) {
        int chunk = w * 128 + c * 64 + lane;
        int row = chunk >> 3, cc = chunk & 7;
        int sw = (cc ^ (row & 7)) << 3;
        async16(Kh + kbh + (size_t)(kv0 + row) * 64 + sw, Ks[0] + (size_t)(w * 128 + c * 64) * 8);
        async16(Vt + vbh + (size_t)row * 2048 + kv0 + sw, Vs[0] + (size_t)(w * 128 + c * 64) * 8);
      }
    }

    for (int t = 0; t < nkv; ++t) {
      const int cur = t & 1;
      __syncthreads();  // drains vmcnt: buf[cur] ready; prev reads of buf[cur^1] done
      if (t + 1 < nkv) {
        int kv0n = (t + 1) * 64;
#pragma unroll
        for (int c = 0; c < 2; ++c) {
          int chunk = w * 128 + c * 64 + lane;
          int row = chunk >> 3, cc = chunk & 7;
          int sw = (cc ^ (row & 7)) << 3;
          async16(Kh + kbh + (size_t)(kv0n + row) * 64 + sw, Ks[cur ^ 1] + (size_t)(w * 128 + c * 64) * 8);
          async16(Vt + vbh + (size_t)row * 2048 + kv0n + sw, Vs[cur ^ 1] + (size_t)(w * 128 + c * 64) * 8);
        }
      }

      // S = Q K^T (per wave: 16 q-rows x 64 keys); scores already in exp2 domain
      f32x4 s[4];
#pragma unroll
      for (int k2 = 0; k2 < 4; ++k2) {
        int key = k2 * 16 + lo;
        bf16x8 kf0 = *(const bf16x8*)(Ks[cur] + key * 64 + ((hi ^ (key & 7)) << 3));
        bf16x8 kf1 = *(const bf16x8*)(Ks[cur] + key * 64 + (((4 + hi) ^ (key & 7)) << 3));
        s[k2] = z4;
        s[k2] = __builtin_amdgcn_mfma_f32_16x16x32_bf16(qf0, kf0, s[k2], 0, 0, 0);
        s[k2] = __builtin_amdgcn_mfma_f32_16x16x32_bf16(qf1, kf1, s[k2], 0, 0, 0);
      }

      const bool diag = (t == qt);  // only the diagonal tile needs causal masking
      float alpha[4];
#pragma unroll
      for (int r = 0; r < 4; ++r) {
        if (diag) {
          int qloc = w * 16 + hi * 4 + r;
#pragma unroll
          for (int k2 = 0; k2 < 4; ++k2)
            if (k2 * 16 + lo > qloc) s[k2][r] = -1e30f;
        }
        float rmax = fmaxf(fmaxf(s[0][r], s[1][r]), fmaxf(s[2][r], s[3][r]));
#pragma unroll
        for (int msk = 8; msk; msk >>= 1) rmax = fmaxf(rmax, __shfl_xor(rmax, msk));
        float mnew = fmaxf(m_r[r], rmax);
        alpha[r] = exp2f(m_r[r] - mnew);
        m_r[r] = mnew;
        float ps = 0.f;
#pragma unroll
        for (int k2 = 0; k2 < 4; ++k2) {
          float p = exp2f(s[k2][r] - mnew);
          ps += p;
          Ps[w][(hi * 4 + r) * 72 + k2 * 16 + lo] = f2bf(p);
        }
#pragma unroll
        for (int msk = 8; msk; msk >>= 1) ps += __shfl_xor(ps, msk);
        l_r[r] = l_r[r] * alpha[r] + ps;
      }

      // PV: O += P @ V   (P via per-wave LDS transpose; DS in-order within wave)
      bf16x8 pf0 = *(const bf16x8*)(Ps[w] + lo * 72 + hi * 8);
      bf16x8 pf1 = *(const bf16x8*)(Ps[w] + lo * 72 + 32 + hi * 8);
#pragma unroll
      for (int dt = 0; dt < 4; ++dt) {
        int d = dt * 16 + lo;
#pragma unroll
        for (int r = 0; r < 4; ++r) O[dt][r] *= alpha[r];
        bf16x8 vf0 = *(const bf16x8*)(Vs[cur] + d * 64 + ((hi ^ (d & 7)) << 3));
        bf16x8 vf1 = *(const bf16x8*)(Vs[cur] + d * 64 + (((4 + hi) ^ (d & 7)) << 3));
        O[dt] = __builtin_amdgcn_mfma_f32_16x16x32_bf16(pf0, vf0, O[dt], 0, 0, 0);
        O[dt] = __builtin_amdgcn_mfma_f32_16x16x32_bf16(pf1, vf1, O[dt], 0, 0, 0);
      }
    }

    // epilogue: ctx[token][h*64+d] bf16
#pragma unroll
    for (int dt = 0; dt < 4; ++dt)
#pragma unroll
      for (int r = 0; r < 4; ++r) {
        int tq = q0 + w * 16 + hi * 4 + r;
        float val = O[dt][r] / l_r[r];
        ctx[((size_t)(b * 2048 + tq)) * 1024 + h * 64 + dt * 16 + lo] = f2bf(val);
      }
  }
}

// ---------- output projection: out = ctx @ w_o (f32 out) ----------
__global__ __launch_bounds__(256) void out_gemm_kernel(const u16* __restrict__ ctxb,
                                                       const u16* __restrict__ Wot,
                                                       float* __restrict__ out) {
  __shared__ u16 As[2][4096];
  __shared__ u16 Bs[2][4096];
  const int m0 = blockIdx.x * 128, n0 = blockIdx.y * 128;
  f32x4 acc[4][4];
  const f32x4 z4 = {0.f, 0.f, 0.f, 0.f};
#pragma unroll
  for (int i = 0; i < 4; ++i)
#pragma unroll
    for (int j = 0; j < 4; ++j) acc[i][j] = z4;
  gemm_mainloop(ctxb, Wot, m0, n0, As, Bs, acc);
  const int tid = threadIdx.x, w = tid >> 6, lane = tid & 63, lo = lane & 15, hi = lane >> 4;
  const int col0 = n0 + (w & 1) * 64 + lo;
#pragma unroll
  for (int mi = 0; mi < 4; ++mi)
#pragma unroll
    for (int r = 0; r < 4; ++r) {
      int tg = m0 + (w >> 1) * 64 + mi * 16 + hi * 4 + r;
#pragma unroll
      for (int nf = 0; nf < 4; ++nf)
        out[(size_t)tg * 1024 + col0 + nf * 16] = acc[mi][nf][r];
    }
}

// ---------- launch ----------
extern "C" void kernel_launch(void* const* d_in, const int* in_sizes, int n_in,
                              void* d_out, int out_size, void* d_ws, size_t ws_size,
                              hipStream_t stream) {
  (void)in_sizes; (void)n_in; (void)out_size; (void)ws_size;
  const float* x  = (const float*)d_in[0];
  const float* wq = (const float*)d_in[1];
  const float* wk = (const float*)d_in[2];
  const float* wv = (const float*)d_in[3];
  const float* wo = (const float*)d_in[4];
  char* ws = (char*)d_ws;
  u16* xb   = (u16*)(ws + (size_t)0);
  u16* Wqt  = (u16*)(ws + ((size_t)8  << 20));
  u16* Wkt  = (u16*)(ws + ((size_t)10 << 20));
  u16* Wvt  = (u16*)(ws + ((size_t)12 << 20));
  u16* Wot  = (u16*)(ws + ((size_t)14 << 20));
  u16* Qh   = (u16*)(ws + ((size_t)16 << 20));
  u16* Kh   = (u16*)(ws + ((size_t)24 << 20));
  u16* Vt   = (u16*)(ws + ((size_t)32 << 20));
  u16* ctxb = (u16*)(ws + ((size_t)40 << 20));

  cvt_kernel<<<4096, 256, 0, stream>>>(x, xb);
  tconv_kernel<<<dim3(16, 16), 256, 0, stream>>>(wq, Wqt);
  tconv_kernel<<<dim3(16, 16), 256, 0, stream>>>(wk, Wkt);
  tconv_kernel<<<dim3(16, 16), 256, 0, stream>>>(wv, Wvt);
  tconv_kernel<<<dim3(16, 16), 256, 0, stream>>>(wo, Wot);
  qkv_gemm_kernel<<<dim3(32, 8, 3), 256, 0, stream>>>(xb, Wqt, Wkt, Wvt, Qh, Kh, Vt);
  attn_kernel<<<dim3(16, 32), 256, 0, stream>>>(Qh, Kh, Vt, ctxb);
  out_gemm_kernel<<<dim3(32, 8), 256, 0, stream>>>(ctxb, Wot, (float*)d_out);
}